// Round 3
// baseline (42.597 us; speedup 1.0000x reference)
//
#include <hip/hip_runtime.h>

#define KMAX 64
#define BB 4
#define LL 4096
#define DD 64
#define TOK (BB * LL)        // 16384 tokens per side
#define SLOTS 8192           // hash-table slots per batch (load factor 0.5)
#define EMPTY 0xFFFFFFFFFFFFFFFFull

typedef unsigned long long u64;

__device__ __forceinline__ int hash_code(int code) {
    return (int)(((unsigned)code * 2654435761u) >> 19) & (SLOTS - 1); // 13 bits
}

// Phase 1: one thread per token-side. Query threads store their code; key
// threads CAS-insert (code<<12 | j) into the per-batch hash table.
// Float accumulation order d=0..63 is bitwise-verified (absmax 0.0) — DO NOT
// change to a tree reduction.
__global__ __launch_bounds__(64) void codes_build_kernel(
        const float* __restrict__ q,
        const float* __restrict__ k,
        const float* __restrict__ W,
        int* __restrict__ qcodes,
        u64* __restrict__ table /* [BB][SLOTS], pre-memset to 0xFF */) {
    __shared__ float sW[DD * 4];
    int lane = threadIdx.x;   // block = 64 = one wave
    #pragma unroll
    for (int i = 0; i < 4; ++i) sW[i * 64 + lane] = W[i * 64 + lane];
    __syncthreads();

    int u = blockIdx.x * 64 + lane;          // grid covers 2*TOK exactly
    const float* src = (u < TOK) ? q : k;
    int t = u & (TOK - 1);

    const float4* xp = (const float4*)(src + (size_t)t * DD);
    float4 x[16];
    #pragma unroll
    for (int i = 0; i < 16; ++i) x[i] = xp[i];

    float p0 = 0.f, p1 = 0.f, p2 = 0.f, p3 = 0.f;
    const float4* wrow = (const float4*)sW;
    #pragma unroll
    for (int d = 0; d < DD; ++d) {
        float xv = ((const float*)x)[d];
        float b = (xv > 0.f) ? 1.0f : 0.0f;      // binary_quantize
        float4 w = wrow[d];
        p0 = fmaf(b, w.x, p0);
        p1 = fmaf(b, w.y, p1);
        p2 = fmaf(b, w.z, p2);
        p3 = fmaf(b, w.w, p3);
    }
    int h0 = ((int)floorf(p0 * 0.5f)) & 31;      // floor(p/2) mod 32
    int h1 = ((int)floorf(p1 * 0.5f)) & 31;
    int h2 = ((int)floorf(p2 * 0.5f)) & 31;
    int h3 = ((int)floorf(p3 * 0.5f)) & 31;
    int code = h0 | (h1 << 5) | (h2 << 10) | (h3 << 15);   // < 2^20

    if (u < TOK) {
        qcodes[u] = code;
    } else {
        int b = t >> 12;                 // batch
        int j = t & (LL - 1);            // key index, 12 bits
        u64 entry = ((u64)(unsigned)code << 12) | (unsigned)j;
        u64* tb = table + (size_t)b * SLOTS;
        int h = hash_code(code);
        for (int step = 0; step < SLOTS; ++step) {
            u64 prev = atomicCAS(&tb[h], EMPTY, entry);
            if (prev == EMPTY) break;    // claimed
            h = (h + 1) & (SLOTS - 1);
        }
    }
}

// Phase 2: one THREAD per query. Probe the table from h(code) until the
// first empty slot; linear-probing invariant guarantees every entry with
// this code lies on that path. Keep the 64 smallest j ascending (capped
// insertion sort in LDS), pad with -1, write as int4.
__global__ __launch_bounds__(64) void query_kernel(
        const int* __restrict__ qcodes,
        const u64* __restrict__ table,
        int* __restrict__ out) {
    __shared__ int cand[64 * 65];        // stride 65 -> bank-conflict-free
    int tid = threadIdx.x;
    int t = blockIdx.x * 64 + tid;       // query id, grid covers TOK exactly
    int b = t >> 12;
    int code = qcodes[t];
    const u64* tb = table + (size_t)b * SLOTS;
    u64 want = (u64)(unsigned)code;
    int* my = cand + tid * 65;
    int cnt = 0;

    int h = hash_code(code);
    for (int step = 0; step < SLOTS; ++step) {
        u64 e = tb[h];
        if (e == EMPTY) break;
        if ((e >> 12) == want) {
            int j = (int)(e & 0xFFF);
            if (cnt < KMAX) {
                int p = cnt++;
                while (p > 0 && my[p - 1] > j) { my[p] = my[p - 1]; --p; }
                my[p] = j;
            } else if (j < my[KMAX - 1]) {
                int p = KMAX - 1;
                while (p > 0 && my[p - 1] > j) { my[p] = my[p - 1]; --p; }
                my[p] = j;
            }
        }
        h = (h + 1) & (SLOTS - 1);
    }
    for (int i = cnt; i < KMAX; ++i) my[i] = -1;

    int4* op = (int4*)(out + (size_t)t * KMAX);
    #pragma unroll
    for (int i = 0; i < 16; ++i)
        op[i] = make_int4(my[4 * i], my[4 * i + 1], my[4 * i + 2], my[4 * i + 3]);
}

extern "C" void kernel_launch(void* const* d_in, const int* in_sizes, int n_in,
                              void* d_out, int out_size, void* d_ws, size_t ws_size,
                              hipStream_t stream) {
    const float* q = (const float*)d_in[0];
    const float* k = (const float*)d_in[1];
    const float* W = (const float*)d_in[2];
    int* out = (int*)d_out;

    int* qcodes = (int*)d_ws;                                  // 16384 ints (64 KB)
    u64* table = (u64*)((char*)d_ws + 65536);                  // 4*8192 u64 (256 KB)

    // Re-init table every call (deterministic; harness doesn't re-poison ws).
    hipMemsetAsync(table, 0xFF, (size_t)BB * SLOTS * sizeof(u64), stream);

    codes_build_kernel<<<(2 * TOK) / 64, 64, 0, stream>>>(q, k, W, qcodes, table);
    query_kernel<<<TOK / 64, 64, 0, stream>>>(qcodes, table, out);
}